// Round 8
// baseline (1541.117 us; speedup 1.0000x reference)
//
#include <hip/hip_runtime.h>

#define T_ 512
#define B_ 256
#define H_ 256
#define DIN_ 64

typedef __attribute__((ext_vector_type(8))) short short8;
typedef __attribute__((ext_vector_type(4))) float f32x4;
typedef __attribute__((ext_vector_type(4))) unsigned int u32x4;

__device__ __forceinline__ unsigned short f2bf(float f) {
  unsigned u = __float_as_uint(f);
  u += 0x7FFFu + ((u >> 16) & 1u);   // RNE
  return (unsigned short)(u >> 16);
}
__device__ __forceinline__ float bf2f(unsigned short s) {
  return __uint_as_float(((unsigned)s) << 16);
}
__device__ __forceinline__ float sigm(float x) { return 1.0f / (1.0f + __expf(-x)); }
__device__ __forceinline__ float tanh_(float x) {
  float xx = fminf(fmaxf(x, -30.0f), 30.0f);
  float e = __expf(2.0f * xx);
  return (e - 1.0f) / (e + 1.0f);
}

// sc1 (agent-scope) loads: bypass L1/L2, read LLC-fresh data. R2/R5-proven.
__device__ __forceinline__ void load16_sc1(const unsigned* p, u32x4& a,
                                           u32x4& b, u32x4& c, u32x4& d) {
  asm volatile(
      "global_load_dwordx4 %0, %4, off sc1\n\t"
      "global_load_dwordx4 %1, %4, off offset:16 sc1\n\t"
      "global_load_dwordx4 %2, %4, off offset:32 sc1\n\t"
      "global_load_dwordx4 %3, %4, off offset:48 sc1\n\t"
      "s_waitcnt vmcnt(0)"
      : "=v"(a), "=v"(b), "=v"(c), "=v"(d)
      : "v"(p) : "memory");
}

__device__ __forceinline__ bool tags_ok(u32x4 a, u32x4 b, u32x4 c, u32x4 d,
                                        unsigned w) {
  unsigned m = (a.x >> 16) ^ w; m |= (a.y >> 16) ^ w;
  m |= (a.z >> 16) ^ w;         m |= (a.w >> 16) ^ w;
  m |= (b.x >> 16) ^ w;         m |= (b.y >> 16) ^ w;
  m |= (b.z >> 16) ^ w;         m |= (b.w >> 16) ^ w;
  m |= (c.x >> 16) ^ w;         m |= (c.y >> 16) ^ w;
  m |= (c.z >> 16) ^ w;         m |= (c.w >> 16) ^ w;
  m |= (d.x >> 16) ^ w;         m |= (d.y >> 16) ^ w;
  m |= (d.z >> 16) ^ w;         m |= (d.w >> 16) ^ w;
  return m == 0;
}

// R8 = R7 design, launch path reverted to R6's validated config:
//  - plain __launch_bounds__(256) (no min-waves arg)
//  - plain <<<>>> launch (no cooperative needed: no grid.sync since R5;
//    64 blocks on 256 CUs are trivially co-resident; hang guards remain)
// Group = 4 wgs. Grid 64 x 256. wg = gb*4 + gc; wg owns 16 batch rows x 64
// h-cols. Wave w owns h-cols [gc*64 + w*16, +16) as 4 MFMA n-tiles; within
// tile t, n = g*4+q -> gate g, h-col gc*64 + w*16 + t*4 + q.
// Per-tile in-wave 4x4 transpose (R6-validated) -> cell update -> 4
// fire-and-forget tagged sc1 stores. One barrier per step.
// Protocol (R5/R6-validated): tag-in-data, parity double-buffered; wg stores
// tag s+1 only after fully acquiring s => no live slot clobbered.
__global__ __launch_bounds__(256) void lstm_kern(
    const float* __restrict__ xin, const float* __restrict__ h0f,
    const float* __restrict__ c0f, const float* __restrict__ Wih,
    const float* __restrict__ Whh, const float* __restrict__ bias,
    const float* __restrict__ Wout, const float* __restrict__ bout,
    float* __restrict__ out, unsigned* hbuf32)
{
  const int tid = threadIdx.x;
  const int gb  = blockIdx.x >> 2;
  const int gc  = blockIdx.x & 3;
  const int wv  = tid >> 6;
  const int ln  = tid & 63;
  const int colB = ln & 15;   // MFMA m (A) / n (B) lane index
  const int krow = ln >> 4;   // MFMA k-quad

  __shared__ unsigned short h_s[2][16 * 264];  // parity-double-buffered
  __shared__ unsigned short x_s[2][16 * 72];

  // ---- W fragments: tile t, n=colB=g*4+q -> row j = g*256 + col ----
  const int gg = colB >> 2, qq = colB & 3;
  short8 bh[4][8], bx[4][2];
  float bval[4];
  #pragma unroll
  for (int t = 0; t < 4; ++t) {
    const int j = gg * H_ + gc * 64 + wv * 16 + t * 4 + qq;  // [0,4H)
    #pragma unroll
    for (int kc = 0; kc < 8; ++kc) {
      const float* p = Whh + j * H_ + kc * 32 + krow * 8;
      float4 v0 = *(const float4*)(p);
      float4 v1 = *(const float4*)(p + 4);
      short8 f;
      f[0] = (short)f2bf(v0.x); f[1] = (short)f2bf(v0.y);
      f[2] = (short)f2bf(v0.z); f[3] = (short)f2bf(v0.w);
      f[4] = (short)f2bf(v1.x); f[5] = (short)f2bf(v1.y);
      f[6] = (short)f2bf(v1.z); f[7] = (short)f2bf(v1.w);
      bh[t][kc] = f;
    }
    #pragma unroll
    for (int kc = 0; kc < 2; ++kc) {
      const float* p = Wih + j * DIN_ + kc * 32 + krow * 8;
      float4 v0 = *(const float4*)(p);
      float4 v1 = *(const float4*)(p + 4);
      short8 f;
      f[0] = (short)f2bf(v0.x); f[1] = (short)f2bf(v0.y);
      f[2] = (short)f2bf(v0.z); f[3] = (short)f2bf(v0.w);
      f[4] = (short)f2bf(v1.x); f[5] = (short)f2bf(v1.y);
      f[6] = (short)f2bf(v1.z); f[7] = (short)f2bf(v1.w);
      bx[t][kc] = f;
    }
    bval[t] = bias[j];
  }

  // element ownership after per-tile transpose: row erow, col cb + t*4
  const int quad = ln >> 4;
  const int r_lo = (ln >> 2) & 3;
  const int q    = ln & 3;
  const int erow = quad * 4 + r_lo;           // row in group (0..15)
  const int grow = gb * 16 + erow;            // global batch row
  const int cb   = gc * 64 + wv * 16 + q;     // col for t=0; +t*4 for tile t
  float c_val[4], h_val[4];
  #pragma unroll
  for (int t = 0; t < 4; ++t) { c_val[t] = c0f[grow * H_ + cb + t * 4]; h_val[t] = 0.f; }

  // hbuf32[2 parity][16 groups][16 rows][256 cols] dwords
  const int hr = tid >> 4;            // consumer row
  const int hcb = (tid & 15) * 16;    // consumer col base (16 dwords)
  const unsigned* ldp_base = hbuf32 + gb * 4096 + hr * 256 + hcb;
  unsigned* stp_base = hbuf32 + gb * 4096 + erow * 256 + cb;

  const float* xrow = xin + ((gb * 16 + (tid >> 4)) * T_) * DIN_ + (tid & 15) * 4;

  for (int s = 1; s <= T_; ++s) {
    const int p = (s - 1) & 1;   // LDS parity for this step's operands
    // ---- stage x_{s-1} -> LDS bf16 (1 float4/thread) ----
    {
      float4 v = *(const float4*)(xrow + (s - 1) * DIN_);
      unsigned short* qp = &x_s[p][(tid >> 4) * 72 + (tid & 15) * 4];
      qp[0] = f2bf(v.x); qp[1] = f2bf(v.y); qp[2] = f2bf(v.z); qp[3] = f2bf(v.w);
    }
    // ---- acquire h^(s-1): tag-validated sc1 loads (the load IS the poll) ----
    if (s == 1) {
      #pragma unroll
      for (int it = 0; it < 4; ++it) {
        int e4 = tid + it * 256;
        int r = e4 >> 6, c4 = e4 & 63;
        float4 v = *((const float4*)(h0f + (gb * 16 + r) * H_) + c4);
        unsigned short* qp = &h_s[p][r * 264 + c4 * 4];
        qp[0] = f2bf(v.x); qp[1] = f2bf(v.y); qp[2] = f2bf(v.z); qp[3] = f2bf(v.w);
      }
    } else {
      const unsigned want = (unsigned)(s - 1);
      const unsigned* ldp = ldp_base + (((s - 1) & 1) << 16);
      u32x4 va, vb, vc, vd;
      int tries = 0;
      do {
        load16_sc1(ldp, va, vb, vc, vd);
        if (tags_ok(va, vb, vc, vd, want)) break;
      } while (++tries < (1 << 18));
      unsigned* q32 = (unsigned*)&h_s[p][hr * 264 + hcb];
      q32[0] = (va.x & 0xFFFFu) | (va.y << 16);
      q32[1] = (va.z & 0xFFFFu) | (va.w << 16);
      q32[2] = (vb.x & 0xFFFFu) | (vb.y << 16);
      q32[3] = (vb.z & 0xFFFFu) | (vb.w << 16);
      q32[4] = (vc.x & 0xFFFFu) | (vc.y << 16);
      q32[5] = (vc.z & 0xFFFFu) | (vc.w << 16);
      q32[6] = (vd.x & 0xFFFFu) | (vd.y << 16);
      q32[7] = (vd.z & 0xFFFFu) | (vd.w << 16);
    }
    __syncthreads();   // the ONLY barrier per step

    // ---- gates: 4 n-tiles, K = 64 (x) + 256 (h); A shared across tiles ----
    f32x4 acc[4];
    #pragma unroll
    for (int t = 0; t < 4; ++t) acc[t] = (f32x4){0.f, 0.f, 0.f, 0.f};
    #pragma unroll
    for (int kc = 0; kc < 2; ++kc) {
      short8 a = *(const short8*)&x_s[p][colB * 72 + kc * 32 + krow * 8];
      #pragma unroll
      for (int t = 0; t < 4; ++t)
        acc[t] = __builtin_amdgcn_mfma_f32_16x16x32_bf16(a, bx[t][kc], acc[t], 0, 0, 0);
    }
    #pragma unroll
    for (int kc = 0; kc < 8; ++kc) {
      short8 a = *(const short8*)&h_s[p][colB * 264 + kc * 32 + krow * 8];
      #pragma unroll
      for (int t = 0; t < 4; ++t)
        acc[t] = __builtin_amdgcn_mfma_f32_16x16x32_bf16(a, bh[t][kc], acc[t], 0, 0, 0);
    }

    // ---- per-tile 4x4 transpose + cell update + tagged store ----
    const unsigned pkhi = (unsigned)s << 16;
    unsigned* stp = stp_base + ((s & 1) << 16);
    #pragma unroll
    for (int t = 0; t < 4; ++t) {
      float v0 = acc[t][0] + bval[t], v1 = acc[t][1] + bval[t],
            v2 = acc[t][2] + bval[t], v3 = acc[t][3] + bval[t];
      {
        int g0 = (ln >> 2) & 1;
        float s0 = g0 ? v0 : v1, s1 = g0 ? v2 : v3;
        float t0 = __shfl_xor(s0, 4, 64), t1 = __shfl_xor(s1, 4, 64);
        if (g0) { v0 = t0; v2 = t1; } else { v1 = t0; v3 = t1; }
      }
      {
        int g1 = (ln >> 3) & 1;
        float s0 = g1 ? v0 : v2, s1 = g1 ? v1 : v3;
        float t0 = __shfl_xor(s0, 8, 64), t1 = __shfl_xor(s1, 8, 64);
        if (g1) { v0 = t0; v1 = t1; } else { v2 = t0; v3 = t1; }
      }
      // v0..v3 = gates i,f,g,o for element (erow, cb + t*4)
      c_val[t] = sigm(v1) * c_val[t] + sigm(v0) * tanh_(v2);
      h_val[t] = sigm(v3) * tanh_(c_val[t]);
      __hip_atomic_store(stp + t * 4, pkhi | (unsigned)f2bf(h_val[t]),
                         __ATOMIC_RELAXED, __HIP_MEMORY_SCOPE_AGENT);
    }
  }

  // ---- outputs: rnn_outputs | logits | h | c ----
  #pragma unroll
  for (int t = 0; t < 4; ++t) {
    const int gj = cb + t * 4;
    out[grow * H_ + gj] = h_val[t];                 // out0: rnn_outputs
    out[67584 + grow * H_ + gj] = h_val[t];         // out2: h   (65536+2048)
    out[133120 + grow * H_ + gj] = c_val[t];        // out3: c
  }

  if (gc == 0) {  // logits for this batch group: need full h^T rows
    const unsigned want = (unsigned)T_;
    const unsigned* ldp = ldp_base + ((T_ & 1) << 16);
    u32x4 va, vb, vc, vd;
    int tries = 0;
    do {
      load16_sc1(ldp, va, vb, vc, vd);
      if (tags_ok(va, vb, vc, vd, want)) break;
    } while (++tries < (1 << 18));
    // stage into parity-0 LDS buffer (last step staged from parity 1)
    unsigned* q32 = (unsigned*)&h_s[0][hr * 264 + hcb];
    q32[0] = (va.x & 0xFFFFu) | (va.y << 16);
    q32[1] = (va.z & 0xFFFFu) | (va.w << 16);
    q32[2] = (vb.x & 0xFFFFu) | (vb.y << 16);
    q32[3] = (vb.z & 0xFFFFu) | (vb.w << 16);
    q32[4] = (vc.x & 0xFFFFu) | (vc.y << 16);
    q32[5] = (vc.z & 0xFFFFu) | (vc.w << 16);
    q32[6] = (vd.x & 0xFFFFu) | (vd.y << 16);
    q32[7] = (vd.z & 0xFFFFu) | (vd.w << 16);
    __syncthreads();   // wg-uniform branch (gc is wg-uniform)
    if (tid < 128) {
      int r = tid >> 3, o = tid & 7;
      float a = bout[o];
      for (int k = 0; k < H_; ++k)
        a = fmaf(bf2f(h_s[0][r * 264 + k]), Wout[o * H_ + k], a);
      out[65536 + (gb * 16 + r) * 8 + o] = a;   // out1: logits
    }
  }
}

extern "C" void kernel_launch(void* const* d_in, const int* in_sizes, int n_in,
                              void* d_out, int out_size, void* d_ws, size_t ws_size,
                              hipStream_t stream) {
  const float* xin  = (const float*)d_in[0];
  const float* h0f  = (const float*)d_in[1];
  const float* c0f  = (const float*)d_in[2];
  const float* Wih  = (const float*)d_in[3];
  const float* Whh  = (const float*)d_in[4];
  const float* bias = (const float*)d_in[5];
  const float* Wout = (const float*)d_in[6];
  const float* bout = (const float*)d_in[7];
  float* out = (float*)d_out;

  // ws: hbuf32[2][16][16][256] dwords (512 KiB)
  unsigned* hbuf32 = (unsigned*)d_ws;

  // Plain launch: no grid.sync since R5; 64 blocks on 256 CUs are trivially
  // co-resident (>=1 block/CU at any occupancy), spin protocol has hang
  // guards. Avoids cooperative-launch occupancy validation entirely.
  lstm_kern<<<dim3(64), dim3(256), 0, stream>>>(
      xin, h0f, c0f, Wih, Whh, bias, Wout, bout, out, hbuf32);
}

// Round 9
// 1390.911 us; speedup vs baseline: 1.1080x; 1.1080x over previous
//
#include <hip/hip_runtime.h>

#define T_ 512
#define B_ 256
#define H_ 256
#define DIN_ 64

typedef __attribute__((ext_vector_type(8))) short short8;
typedef __attribute__((ext_vector_type(4))) float f32x4;
typedef __attribute__((ext_vector_type(4))) unsigned int u32x4;

__device__ __forceinline__ unsigned short f2bf(float f) {
  unsigned u = __float_as_uint(f);
  u += 0x7FFFu + ((u >> 16) & 1u);   // RNE
  return (unsigned short)(u >> 16);
}
__device__ __forceinline__ float bf2f(unsigned short s) {
  return __uint_as_float(((unsigned)s) << 16);
}
__device__ __forceinline__ float sigm(float x) { return 1.0f / (1.0f + __expf(-x)); }
__device__ __forceinline__ float tanh_(float x) {
  float xx = fminf(fmaxf(x, -30.0f), 30.0f);
  float e = __expf(2.0f * xx);
  return (e - 1.0f) / (e + 1.0f);
}

// Fallback path (R2/R5-proven correct): sc1 loads read globally-fresh data.
__device__ __forceinline__ void load16_sc1(const unsigned* p, u32x4& a,
                                           u32x4& b, u32x4& c, u32x4& d) {
  asm volatile(
      "global_load_dwordx4 %0, %4, off sc1\n\t"
      "global_load_dwordx4 %1, %4, off offset:16 sc1\n\t"
      "global_load_dwordx4 %2, %4, off offset:32 sc1\n\t"
      "global_load_dwordx4 %3, %4, off offset:48 sc1\n\t"
      "s_waitcnt vmcnt(0)"
      : "=v"(a), "=v"(b), "=v"(c), "=v"(d)
      : "v"(p) : "memory");
}

__device__ __forceinline__ bool tags_ok(u32x4 a, u32x4 b, u32x4 c, u32x4 d,
                                        unsigned w) {
  unsigned m = (a.x >> 16) ^ w; m |= (a.y >> 16) ^ w;
  m |= (a.z >> 16) ^ w;         m |= (a.w >> 16) ^ w;
  m |= (b.x >> 16) ^ w;         m |= (b.y >> 16) ^ w;
  m |= (b.z >> 16) ^ w;         m |= (b.w >> 16) ^ w;
  m |= (c.x >> 16) ^ w;         m |= (c.y >> 16) ^ w;
  m |= (c.z >> 16) ^ w;         m |= (c.w >> 16) ^ w;
  m |= (d.x >> 16) ^ w;         m |= (d.y >> 16) ^ w;
  m |= (d.z >> 16) ^ w;         m |= (d.w >> 16) ^ w;
  return m == 0;
}

// R9 = R6 structure (256 wgs, 16-wg groups, 1 barrier/step, in-wave 4x4
// transpose, fire-and-forget tagged stores, parity double-buffer) with the
// consumer poll switched from sc1 loads (HBM-latency round trips; FETCH_SIZE
// evidence R5/R8) to device-scope 64-bit atomic_fetch_or(p,0) — atomics
// execute at the MALL (device coherence point): lower RT, lines stay
// MALL-resident (also lets producer stores merge at MALL, killing the
// write-allocate HBM fills). sc1 path kept as correctness fallback.
// Plain (non-cooperative) launch — R8-validated; no grid.sync since R5.
__global__ __launch_bounds__(256) void lstm_kern(
    const float* __restrict__ xin, const float* __restrict__ h0f,
    const float* __restrict__ c0f, const float* __restrict__ Wih,
    const float* __restrict__ Whh, const float* __restrict__ bias,
    const float* __restrict__ Wout, const float* __restrict__ bout,
    float* __restrict__ out, unsigned* hbuf32)
{
  const int tid = threadIdx.x;
  const int gb  = blockIdx.x >> 4;
  const int gc  = blockIdx.x & 15;
  const int wv  = tid >> 6;
  const int ln  = tid & 63;
  const int colB = ln & 15;   // MFMA n
  const int krow = ln >> 4;   // MFMA k-quad

  __shared__ unsigned short h_s[2][16 * 264];  // parity-double-buffered
  __shared__ unsigned short x_s[2][16 * 72];

  // ---- W fragments, gate-interleaved N mapping: n=g*4+q -> row g*256+... ----
  const int gg = colB >> 2, qq = colB & 3;
  const int j = gg * H_ + gc * 16 + wv * 4 + qq;   // row in [0,4H)
  short8 bh[8], bx[2];
  #pragma unroll
  for (int kc = 0; kc < 8; ++kc) {
    const float* p = Whh + j * H_ + kc * 32 + krow * 8;
    short8 f;
    #pragma unroll
    for (int i = 0; i < 8; ++i) f[i] = (short)f2bf(p[i]);
    bh[kc] = f;
  }
  #pragma unroll
  for (int kc = 0; kc < 2; ++kc) {
    const float* p = Wih + j * DIN_ + kc * 32 + krow * 8;
    short8 f;
    #pragma unroll
    for (int i = 0; i < 8; ++i) f[i] = (short)f2bf(p[i]);
    bx[kc] = f;
  }
  const float bval = bias[j];

  // element owned after transpose: row quad*4 + r_lo, col gc*16 + wv*4 + q
  const int quad = ln >> 4;
  const int r_lo = (ln >> 2) & 3;
  const int q    = ln & 3;
  const int erow = quad * 4 + r_lo;          // row in group (0..15)
  const int grow = gb * 16 + erow;           // global batch row
  const int gcol = gc * 16 + wv * 4 + q;     // global h col
  float c_val = c0f[grow * H_ + gcol];
  float h_val = 0.0f;

  // hbuf32[2 parity][16 groups][16 rows][256 cols] dwords
  const int hr = tid >> 4;            // consumer row
  const int hcb = (tid & 15) * 16;    // consumer col base (16 dwords)
  const unsigned* ldp_base = hbuf32 + gb * 4096 + hr * 256 + hcb;
  unsigned* stp_base = hbuf32 + gb * 4096 + erow * 256 + gcol;

  const float* xrow = xin + ((gb * 16 + (tid >> 4)) * T_) * DIN_ + (tid & 15) * 4;

  for (int s = 1; s <= T_; ++s) {
    const int p = (s - 1) & 1;   // LDS parity for this step's operands
    // ---- stage x_{s-1} -> LDS bf16 (1 float4/thread) ----
    {
      float4 v = *(const float4*)(xrow + (s - 1) * DIN_);
      unsigned short* qp = &x_s[p][(tid >> 4) * 72 + (tid & 15) * 4];
      qp[0] = f2bf(v.x); qp[1] = f2bf(v.y); qp[2] = f2bf(v.z); qp[3] = f2bf(v.w);
    }
    // ---- acquire h^(s-1) ----
    if (s == 1) {
      #pragma unroll
      for (int it = 0; it < 4; ++it) {
        int e4 = tid + it * 256;
        int r = e4 >> 6, c4 = e4 & 63;
        float4 v = *((const float4*)(h0f + (gb * 16 + r) * H_) + c4);
        unsigned short* qp = &h_s[p][r * 264 + c4 * 4];
        qp[0] = f2bf(v.x); qp[1] = f2bf(v.y); qp[2] = f2bf(v.z); qp[3] = f2bf(v.w);
      }
    } else {
      const unsigned want = (unsigned)(s - 1);
      unsigned long long* ldq = (unsigned long long*)(ldp_base + (((s - 1) & 1) << 16));
      unsigned long long r0, r1, r2, r3, r4, r5, r6, r7;
      bool ok = false;
      // ---- primary poll: device-scope atomic loads (execute at MALL) ----
      for (int t = 0; t < 4096 && !ok; ++t) {
        r0 = __hip_atomic_fetch_or(ldq + 0, 0ull, __ATOMIC_RELAXED, __HIP_MEMORY_SCOPE_AGENT);
        r1 = __hip_atomic_fetch_or(ldq + 1, 0ull, __ATOMIC_RELAXED, __HIP_MEMORY_SCOPE_AGENT);
        r2 = __hip_atomic_fetch_or(ldq + 2, 0ull, __ATOMIC_RELAXED, __HIP_MEMORY_SCOPE_AGENT);
        r3 = __hip_atomic_fetch_or(ldq + 3, 0ull, __ATOMIC_RELAXED, __HIP_MEMORY_SCOPE_AGENT);
        r4 = __hip_atomic_fetch_or(ldq + 4, 0ull, __ATOMIC_RELAXED, __HIP_MEMORY_SCOPE_AGENT);
        r5 = __hip_atomic_fetch_or(ldq + 5, 0ull, __ATOMIC_RELAXED, __HIP_MEMORY_SCOPE_AGENT);
        r6 = __hip_atomic_fetch_or(ldq + 6, 0ull, __ATOMIC_RELAXED, __HIP_MEMORY_SCOPE_AGENT);
        r7 = __hip_atomic_fetch_or(ldq + 7, 0ull, __ATOMIC_RELAXED, __HIP_MEMORY_SCOPE_AGENT);
        unsigned m;
        m  = ((unsigned)(r0 >> 16) & 0xFFFFu) ^ want;  m |= ((unsigned)(r0 >> 48)) ^ want;
        m |= ((unsigned)(r1 >> 16) & 0xFFFFu) ^ want;  m |= ((unsigned)(r1 >> 48)) ^ want;
        m |= ((unsigned)(r2 >> 16) & 0xFFFFu) ^ want;  m |= ((unsigned)(r2 >> 48)) ^ want;
        m |= ((unsigned)(r3 >> 16) & 0xFFFFu) ^ want;  m |= ((unsigned)(r3 >> 48)) ^ want;
        m |= ((unsigned)(r4 >> 16) & 0xFFFFu) ^ want;  m |= ((unsigned)(r4 >> 48)) ^ want;
        m |= ((unsigned)(r5 >> 16) & 0xFFFFu) ^ want;  m |= ((unsigned)(r5 >> 48)) ^ want;
        m |= ((unsigned)(r6 >> 16) & 0xFFFFu) ^ want;  m |= ((unsigned)(r6 >> 48)) ^ want;
        m |= ((unsigned)(r7 >> 16) & 0xFFFFu) ^ want;  m |= ((unsigned)(r7 >> 48)) ^ want;
        ok = (m == 0);
      }
      unsigned* q32 = (unsigned*)&h_s[p][hr * 264 + hcb];
      if (ok) {
        q32[0] = (unsigned)(r0 & 0xFFFFu) | (((unsigned)(r0 >> 32) & 0xFFFFu) << 16);
        q32[1] = (unsigned)(r1 & 0xFFFFu) | (((unsigned)(r1 >> 32) & 0xFFFFu) << 16);
        q32[2] = (unsigned)(r2 & 0xFFFFu) | (((unsigned)(r2 >> 32) & 0xFFFFu) << 16);
        q32[3] = (unsigned)(r3 & 0xFFFFu) | (((unsigned)(r3 >> 32) & 0xFFFFu) << 16);
        q32[4] = (unsigned)(r4 & 0xFFFFu) | (((unsigned)(r4 >> 32) & 0xFFFFu) << 16);
        q32[5] = (unsigned)(r5 & 0xFFFFu) | (((unsigned)(r5 >> 32) & 0xFFFFu) << 16);
        q32[6] = (unsigned)(r6 & 0xFFFFu) | (((unsigned)(r6 >> 32) & 0xFFFFu) << 16);
        q32[7] = (unsigned)(r7 & 0xFFFFu) | (((unsigned)(r7 >> 32) & 0xFFFFu) << 16);
      } else {
        // ---- fallback: sc1 loads (R5-proven) ----
        const unsigned* ldp = ldp_base + (((s - 1) & 1) << 16);
        u32x4 va, vb, vc, vd;
        int tries = 0;
        do {
          load16_sc1(ldp, va, vb, vc, vd);
          if (tags_ok(va, vb, vc, vd, want)) break;
        } while (++tries < (1 << 18));
        q32[0] = (va.x & 0xFFFFu) | (va.y << 16);
        q32[1] = (va.z & 0xFFFFu) | (va.w << 16);
        q32[2] = (vb.x & 0xFFFFu) | (vb.y << 16);
        q32[3] = (vb.z & 0xFFFFu) | (vb.w << 16);
        q32[4] = (vc.x & 0xFFFFu) | (vc.y << 16);
        q32[5] = (vc.z & 0xFFFFu) | (vc.w << 16);
        q32[6] = (vd.x & 0xFFFFu) | (vd.y << 16);
        q32[7] = (vd.z & 0xFFFFu) | (vd.w << 16);
      }
    }
    __syncthreads();   // the ONLY barrier per step

    // ---- gates: K = 64 (x) + 256 (h), n = gate-interleaved ----
    f32x4 acc = {0.f, 0.f, 0.f, 0.f};
    #pragma unroll
    for (int kc = 0; kc < 2; ++kc) {
      short8 a = *(const short8*)&x_s[p][colB * 72 + kc * 32 + krow * 8];
      acc = __builtin_amdgcn_mfma_f32_16x16x32_bf16(a, bx[kc], acc, 0, 0, 0);
    }
    #pragma unroll
    for (int kc = 0; kc < 8; ++kc) {
      short8 a = *(const short8*)&h_s[p][colB * 264 + kc * 32 + krow * 8];
      acc = __builtin_amdgcn_mfma_f32_16x16x32_bf16(a, bh[kc], acc, 0, 0, 0);
    }

    // ---- in-wave 4x4 transpose: lane bits 2-3 (gate) <-> reg idx (row) ----
    float v0 = acc[0] + bval, v1 = acc[1] + bval,
          v2 = acc[2] + bval, v3 = acc[3] + bval;
    {
      int g0 = (ln >> 2) & 1;
      float s0 = g0 ? v0 : v1, s1 = g0 ? v2 : v3;
      float t0 = __shfl_xor(s0, 4, 64), t1 = __shfl_xor(s1, 4, 64);
      if (g0) { v0 = t0; v2 = t1; } else { v1 = t0; v3 = t1; }
    }
    {
      int g1 = (ln >> 3) & 1;
      float s0 = g1 ? v0 : v2, s1 = g1 ? v1 : v3;
      float t0 = __shfl_xor(s0, 8, 64), t1 = __shfl_xor(s1, 8, 64);
      if (g1) { v0 = t0; v1 = t1; } else { v2 = t0; v3 = t1; }
    }
    // v0..v3 = gates i,f,g,o for element (erow, gcol)

    // ---- cell update + fire-and-forget tagged store (no barrier) ----
    c_val = sigm(v1) * c_val + sigm(v0) * tanh_(v2);
    h_val = sigm(v3) * tanh_(c_val);
    unsigned pk = ((unsigned)s << 16) | (unsigned)f2bf(h_val);
    __hip_atomic_store(stp_base + ((s & 1) << 16), pk,
                       __ATOMIC_RELAXED, __HIP_MEMORY_SCOPE_AGENT);
  }

  // ---- outputs: rnn_outputs | logits | h | c ----
  out[grow * H_ + gcol] = h_val;                 // out0: rnn_outputs
  out[67584 + grow * H_ + gcol] = h_val;         // out2: h   (65536+2048)
  out[133120 + grow * H_ + gcol] = c_val;        // out3: c

  if (gc == 0) {  // logits for this batch group: need full h^T rows
    const unsigned want = (unsigned)T_;
    const unsigned* ldp = ldp_base + ((T_ & 1) << 16);
    u32x4 va, vb, vc, vd;
    int tries = 0;
    do {
      load16_sc1(ldp, va, vb, vc, vd);
      if (tags_ok(va, vb, vc, vd, want)) break;
    } while (++tries < (1 << 18));
    unsigned* q32 = (unsigned*)&h_s[0][hr * 264 + hcb];
    q32[0] = (va.x & 0xFFFFu) | (va.y << 16);
    q32[1] = (va.z & 0xFFFFu) | (va.w << 16);
    q32[2] = (vb.x & 0xFFFFu) | (vb.y << 16);
    q32[3] = (vb.z & 0xFFFFu) | (vb.w << 16);
    q32[4] = (vc.x & 0xFFFFu) | (vc.y << 16);
    q32[5] = (vc.z & 0xFFFFu) | (vc.w << 16);
    q32[6] = (vd.x & 0xFFFFu) | (vd.y << 16);
    q32[7] = (vd.z & 0xFFFFu) | (vd.w << 16);
    __syncthreads();   // wg-uniform branch (gc is wg-uniform)
    if (tid < 128) {
      int r = tid >> 3, o = tid & 7;
      float a = bout[o];
      for (int k = 0; k < H_; ++k)
        a = fmaf(bf2f(h_s[0][r * 264 + k]), Wout[o * H_ + k], a);
      out[65536 + (gb * 16 + r) * 8 + o] = a;   // out1: logits
    }
  }
}

extern "C" void kernel_launch(void* const* d_in, const int* in_sizes, int n_in,
                              void* d_out, int out_size, void* d_ws, size_t ws_size,
                              hipStream_t stream) {
  const float* xin  = (const float*)d_in[0];
  const float* h0f  = (const float*)d_in[1];
  const float* c0f  = (const float*)d_in[2];
  const float* Wih  = (const float*)d_in[3];
  const float* Whh  = (const float*)d_in[4];
  const float* bias = (const float*)d_in[5];
  const float* Wout = (const float*)d_in[6];
  const float* bout = (const float*)d_in[7];
  float* out = (float*)d_out;

  // ws: hbuf32[2][16][16][256] dwords (512 KiB)
  unsigned* hbuf32 = (unsigned*)d_ws;

  lstm_kern<<<dim3(256), dim3(256), 0, stream>>>(
      xin, h0f, c0f, Wih, Whh, bias, Wout, bout, out, hbuf32);
}